// Round 4
// baseline (155.752 us; speedup 1.0000x reference)
//
#include <hip/hip_runtime.h>
#include <hip/hip_bf16.h>

typedef __attribute__((ext_vector_type(8))) short short8;
typedef __attribute__((ext_vector_type(4))) float f32x4;
typedef __attribute__((ext_vector_type(4))) unsigned int u32x4;

#define XS_BYTES 73728   // 8 slots * 144 rows * 64 B (32-bf16 c-half), swizzled

// involution swizzle: XOR bank-group bits (4-5) with row bits (7-8)
__device__ __forceinline__ unsigned sw(unsigned off) {
  return off ^ (((off >> 7) & 3u) << 4);
}

__device__ __forceinline__ unsigned pk2(float lo, float hi) {
  union { __hip_bfloat162 h; unsigned u; } c;
  c.h = __float22bfloat162_rn(float2{lo, hi});
  return c.u;
}

// one-time: ker (fp32, N*K x F x C) -> bf16 fragment-linear in ws
// frag(ch,nk,ft,lane) holds W[f=ft*16+(lane&15), c=ch*32+(lane>>4)*8 .. +8]
extern "C" __global__ void w_prep(const float* __restrict__ ker, u32x4* __restrict__ wsw) {
  const int nk = blockIdx.x % 36;
  const int ch = blockIdx.x / 36;
  const int lane = threadIdx.x & 63;
  const int ft = threadIdx.x >> 6;
  const float* src = ker + (size_t)(nk * 64 + ft * 16 + (lane & 15)) * 64
                         + ch * 32 + (lane >> 4) * 8;
  f32x4 a0 = *(const f32x4*)src;
  f32x4 a1 = *(const f32x4*)(src + 4);
  u32x4 h = { pk2(a0.x, a0.y), pk2(a0.z, a0.w), pk2(a1.x, a1.y), pk2(a1.z, a1.w) };
  wsw[((ch * 36 + nk) * 4 + ft) * 64 + lane] = h;
}

extern "C" __global__ __launch_bounds__(256, 2)
void glc_mfma(const float* __restrict__ x, const short8* __restrict__ wsw,
              const int* __restrict__ nb, float* __restrict__ out) {
  __shared__ __align__(16) char xs[XS_BYTES];

  const int bid = blockIdx.x;
  const int tt = bid % 5;
  const int up = (bid / 5) % 13;
  const int a  = (bid / 65) % 3;
  const int b  = bid / 195;
  const int t0 = tt * 64;
  const int u0 = up * 2;
  const bool updup = (up == 12);   // u-pair (24,24): waves 2,3 duplicate

  const int tid  = threadIdx.x;
  const int lane = tid & 63;
  const int wave = tid >> 6;
  const int uloc = wave >> 1;

  // x-staging roles: slot = (uloc*4+n), 32 threads per slot
  const int sslot = tid >> 5;
  const int scu   = tid & 3;            // c-octet
  const int srr   = (tid >> 2) & 7;
  const int su    = u0 + ((updup ? 0 : 1) & (sslot >> 2));
  const int sv    = nb[su * 4 + (sslot & 3)];

  // B-fragment swizzled row-part offsets: full addr = slot*9216 + q*512 + poff[i][k&3]
  // (swizzle key is independent of slot and q by construction)
  const int rl = lane & 15, gq = lane >> 4;
  unsigned poff[4][4];
#pragma unroll
  for (int i = 0; i < 4; ++i) {
    const int ctl = (wave * 4 + i) & 7;
#pragma unroll
    for (int m = 0; m < 4; ++m)
      poff[i][m] = sw((unsigned)((ctl * 16 + 2 * m + rl) * 64 + gq * 16));
  }

  f32x4 acc[4][4];
#pragma unroll
  for (int i = 0; i < 4; ++i)
#pragma unroll
    for (int j = 0; j < 4; ++j) acc[i][j] = (f32x4){0.f, 0.f, 0.f, 0.f};

  const float* xb = x + (size_t)b * (300 * 9600) + (size_t)a * 3200 + (sv * 2) * 64 + scu * 8;

#pragma unroll 1
  for (int ch = 0; ch < 2; ++ch) {
    if (ch) __syncthreads();            // protect prev-half reads
#pragma unroll 3
    for (int it = 0; it < 18; ++it) {
      int r = it * 8 + srr;
      int t = t0 + (r >> 1); if (t > 299) t = 299;   // clamp; garbage discarded
      const float* src = xb + (size_t)t * 9600 + (r & 1) * 64 + ch * 32;
      f32x4 a0 = *(const f32x4*)src;
      f32x4 a1 = *(const f32x4*)(src + 4);
      u32x4 h = { pk2(a0.x, a0.y), pk2(a0.z, a0.w), pk2(a1.x, a1.y), pk2(a1.z, a1.w) };
      unsigned off = (unsigned)(sslot * 9216 + r * 64 + scu * 16);
      *(u32x4*)(xs + sw(off)) = h;
    }
    __syncthreads();

    const short8* wq = wsw + (size_t)ch * 9216 + lane;   // (ch, nk, ft, lane)

    // pipeline prologue: W[0], B[n=0,k=0]
    short8 wcur[4], bcur[4];
#pragma unroll
    for (int ft = 0; ft < 4; ++ft) wcur[ft] = wq[ft * 64];
    unsigned sbase = (unsigned)(uloc * 4 * 9216);
#pragma unroll
    for (int i = 0; i < 4; ++i)
      bcur[i] = *(const short8*)(xs + (sbase + poff[i][0]));

#pragma unroll 1
    for (int n = 0; n < 4; ++n) {
#pragma unroll
      for (int k = 0; k < 9; ++k) {
        const int nk = n * 9 + k;
        const bool hn = (nk < 35);
        short8 wnxt[4], bnxt[4];
        if (hn) {
          // prefetch next-nk W (global, L1/L2-resident) and B (LDS) before MFMAs
#pragma unroll
          for (int ft = 0; ft < 4; ++ft)
            wnxt[ft] = wq[(nk + 1) * 256 + ft * 64];
          if (k < 8) {
            const unsigned ub = sbase + (unsigned)((((k + 1) >> 2)) * 512);
#pragma unroll
            for (int i = 0; i < 4; ++i)
              bnxt[i] = *(const short8*)(xs + (ub + poff[i][(k + 1) & 3]));
          } else {
            const unsigned ub = sbase + 9216;   // next n slot, k=0
#pragma unroll
            for (int i = 0; i < 4; ++i)
              bnxt[i] = *(const short8*)(xs + (ub + poff[i][0]));
          }
        }
#pragma unroll
        for (int i = 0; i < 4; ++i)
#pragma unroll
          for (int ft = 0; ft < 4; ++ft)
            acc[ft][i] = __builtin_amdgcn_mfma_f32_16x16x32_bf16(wcur[ft], bcur[i], acc[ft][i], 0, 0, 0);
        if (hn) {
#pragma unroll
          for (int ft = 0; ft < 4; ++ft) wcur[ft] = wnxt[ft];
#pragma unroll
          for (int i = 0; i < 4; ++i) bcur[i] = bnxt[i];
        }
      }
      sbase += 9216;
    }
  }

  // ---- epilogue: D tile (ft,i): col = lane&15, f = ft*16 + (lane>>4)*4 + reg ----
  if (updup && uloc) return;            // skip duplicate u=24 stores
  const int u = u0 + uloc;
  const int fbase = (lane >> 4) * 4;
  const f32x4 z4 = (f32x4){0.f, 0.f, 0.f, 0.f};
#pragma unroll
  for (int i = 0; i < 4; ++i) {
    const int colg = wave * 64 + i * 16 + (lane & 15);
    const int cc = colg & 127;          // within-u column: t-rel (p-minor)
    const int t = t0 + (cc >> 1);
    const int p = cc & 1;
    if (t < 300) {
      float* dst = out + ((size_t)((b * 300 + t) * 3 + a) * 50 + (u * 2 + p)) * 64 + fbase;
      const bool valid = (t < 292);     // t>=292: zero-pad tail
#pragma unroll
      for (int ft = 0; ft < 4; ++ft) {
        f32x4 v = valid ? acc[ft][i] : z4;
        *(f32x4*)(dst + ft * 16) = v;
      }
    }
  }
}

extern "C" void kernel_launch(void* const* d_in, const int* in_sizes, int n_in,
                              void* d_out, int out_size, void* d_ws, size_t ws_size,
                              hipStream_t stream) {
  const float* x   = (const float*)d_in[0];
  const float* ker = (const float*)d_in[1];
  const int*   nb  = (const int*)d_in[2];
  float* out = (float*)d_out;

  w_prep<<<dim3(72), dim3(256), 0, stream>>>(ker, (u32x4*)d_ws);
  glc_mfma<<<dim3(8 * 3 * 13 * 5), dim3(256), 0, stream>>>(x, (const short8*)d_ws, nb, out);
}